// Round 9
// baseline (921.825 us; speedup 1.0000x reference)
//
#include <hip/hip_runtime.h>
#include <hip/hip_bf16.h>

#define HEADS 3
#define HID 64
#define OUTW (HEADS * HID)   // 192
#define NS 128               // node feature size

__device__ __forceinline__ float lrelu(float x) {
    return x > 0.f ? x : 0.2f * x;
}

__device__ __forceinline__ unsigned short f2bf(float f) {
    unsigned u = __float_as_uint(f);
    u += 0x7fff + ((u >> 16) & 1);   // RNE
    return (unsigned short)(u >> 16);
}

__device__ __forceinline__ float bf2f(unsigned short u) {
    return __uint_as_float((unsigned)u << 16);
}

// ---------------- CSR build (by dst) ----------------

__global__ void k_zero_int(int* p, int n) {
    int i = blockIdx.x * blockDim.x + threadIdx.x;
    for (; i < n; i += gridDim.x * blockDim.x) p[i] = 0;
}

__global__ void k_hist(const int* __restrict__ key, int* __restrict__ cnt, int E) {
    int i = blockIdx.x * blockDim.x + threadIdx.x;
    for (; i < E; i += gridDim.x * blockDim.x) atomicAdd(&cnt[key[i]], 1);
}

__global__ void k_scan1(const int* __restrict__ cnt, int* __restrict__ rowstart,
                        int* __restrict__ blocksums, int N) {
    int t = threadIdx.x;
    int base = blockIdx.x * 1024 + t * 4;
    int v[4];
    int ts = 0;
#pragma unroll
    for (int j = 0; j < 4; ++j) {
        v[j] = (base + j < N) ? cnt[base + j] : 0;
        ts += v[j];
    }
    __shared__ int sh[256];
    sh[t] = ts;
    __syncthreads();
    for (int off = 1; off < 256; off <<= 1) {
        int x = 0;
        if (t >= off) x = sh[t - off];
        __syncthreads();
        if (t >= off) sh[t] += x;
        __syncthreads();
    }
    int excl = sh[t] - ts;
    if (t == 255) blocksums[blockIdx.x] = sh[255];
    int run = excl;
#pragma unroll
    for (int j = 0; j < 4; ++j) {
        if (base + j < N) rowstart[base + j] = run;
        run += v[j];
    }
}

__global__ void k_scan2(int* blocksums, int nb) {
    if (blockIdx.x == 0 && threadIdx.x == 0) {
        int s = 0;
        for (int i = 0; i < nb; ++i) {
            int v = blocksums[i];
            blocksums[i] = s;
            s += v;
        }
    }
}

__global__ void k_scan3(int* __restrict__ rowstart, const int* __restrict__ blocksums,
                        int* __restrict__ cursor, int N, int E) {
    int i = blockIdx.x * blockDim.x + threadIdx.x;
    if (i < N) {
        int v = rowstart[i] + blocksums[i >> 10];
        rowstart[i] = v;
        cursor[i] = v;
    }
    if (i == 0) rowstart[N] = E;
}

__global__ void k_scatter(const int* __restrict__ val, const int* __restrict__ key,
                          int* __restrict__ cursor, int* __restrict__ outidx, int E) {
    int i = blockIdx.x * blockDim.x + threadIdx.x;
    for (; i < E; i += gridDim.x * blockDim.x) {
        int d = key[i];
        int p = atomicAdd(&cursor[d], 1);
        outidx[p] = val[i];
    }
}

// ---------------- prep: wl1/wr1[k,h] = sum_f W1[k, h*64+f] * al1/ar1[h,f] ------

__global__ void k_prep(const float* __restrict__ W1, const float* __restrict__ al1,
                       const float* __restrict__ ar1, float* __restrict__ wlr1) {
    int t = threadIdx.x;
    if (t >= 192) return;
    int k = t & 63, hh = t >> 6;
    float sl = 0.f, sr = 0.f;
#pragma unroll 8
    for (int f = 0; f < 64; ++f) {
        float w = W1[k * OUTW + hh * 64 + f];
        sl = fmaf(w, al1[hh * 64 + f], sl);
        sr = fmaf(w, ar1[hh * 64 + f], sr);
    }
    wlr1[k * 8 + hh] = sl;
    wlr1[k * 8 + 4 + hh] = sr;
}

// ---------------- GEMM0: Z16[M,192](bf16) = X[M,128] @ W0, fused el0/er0 --------

template <int K>
__global__ __launch_bounds__(256, 2) void k_gemm4(const float* __restrict__ X,
                                                  const float* __restrict__ W,
                                                  const float* __restrict__ al,
                                                  const float* __restrict__ ar,
                                                  unsigned short* __restrict__ Z16,
                                                  float* __restrict__ elr,
                                                  int M) {
    constexpr int NT = K / 16;
    __shared__ __align__(16) float At[2][16 * 132];
    __shared__ __align__(16) float Bs[2][16 * 192];
    const int tid = threadIdx.x;
    const int tx = tid & 15;
    const int ty = tid >> 4;
    const int r0 = blockIdx.x * 128;

    float acc[8][12];
#pragma unroll
    for (int i = 0; i < 8; ++i)
#pragma unroll
        for (int j = 0; j < 12; ++j) acc[i][j] = 0.f;

    const int arow = tid >> 2;
    const int akb = (tid & 3) * 4;

    float4 aR[2], bR[3];

    auto loadA = [&](int k0) {
#pragma unroll
        for (int i = 0; i < 2; ++i) {
            int gr = r0 + arow + i * 64;
            if (gr >= M) gr = M - 1;
            aR[i] = *(const float4*)(X + (size_t)gr * K + k0 + akb);
        }
    };
    auto loadB = [&](int k0) {
#pragma unroll
        for (int i = 0; i < 3; ++i)
            bR[i] = *(const float4*)(W + (size_t)k0 * OUTW + (tid + i * 256) * 4);
    };
    auto writeA = [&](int buf) {
#pragma unroll
        for (int i = 0; i < 2; ++i) {
            int row = arow + i * 64;
            At[buf][(akb + 0) * 132 + row] = aR[i].x;
            At[buf][(akb + 1) * 132 + row] = aR[i].y;
            At[buf][(akb + 2) * 132 + row] = aR[i].z;
            At[buf][(akb + 3) * 132 + row] = aR[i].w;
        }
    };
    auto writeB = [&](int buf) {
#pragma unroll
        for (int i = 0; i < 3; ++i)
            *(float4*)(&Bs[buf][(tid + i * 256) * 4]) = bR[i];
    };

    loadA(0);
    loadB(0);
    writeA(0);
    writeB(0);
    __syncthreads();

    int cur = 0;
    for (int t = 0; t < NT; ++t) {
        if (t + 1 < NT) {
            loadA((t + 1) * 16);
            loadB((t + 1) * 16);
        }
#pragma unroll 8
        for (int k = 0; k < 16; ++k) {
            float a[8], b[12];
            *(float4*)&a[0] = *(const float4*)&At[cur][k * 132 + ty * 8];
            *(float4*)&a[4] = *(const float4*)&At[cur][k * 132 + ty * 8 + 4];
            *(float4*)&b[0] = *(const float4*)&Bs[cur][k * OUTW + tx * 4];
            *(float4*)&b[4] = *(const float4*)&Bs[cur][k * OUTW + 64 + tx * 4];
            *(float4*)&b[8] = *(const float4*)&Bs[cur][k * OUTW + 128 + tx * 4];
#pragma unroll
            for (int i = 0; i < 8; ++i)
#pragma unroll
                for (int j = 0; j < 12; ++j) acc[i][j] = fmaf(a[i], b[j], acc[i][j]);
        }
        if (t + 1 < NT) {
            writeA(cur ^ 1);
            writeB(cur ^ 1);
        }
        __syncthreads();
        cur ^= 1;
    }

    float alr[12], arr[12];
#pragma unroll
    for (int h = 0; h < HEADS; ++h)
#pragma unroll
        for (int c = 0; c < 4; ++c) {
            alr[h * 4 + c] = al[h * 64 + tx * 4 + c];
            arr[h * 4 + c] = ar[h * 64 + tx * 4 + c];
        }

#pragma unroll
    for (int i = 0; i < 8; ++i) {
        int row = r0 + ty * 8 + i;
        bool live = row < M;
        if (live) {
#pragma unroll
            for (int h = 0; h < HEADS; ++h) {
                ushort4 v;
                v.x = f2bf(acc[i][h * 4 + 0]);
                v.y = f2bf(acc[i][h * 4 + 1]);
                v.z = f2bf(acc[i][h * 4 + 2]);
                v.w = f2bf(acc[i][h * 4 + 3]);
                *(ushort4*)(Z16 + (size_t)row * OUTW + h * 64 + tx * 4) = v;
            }
        }
        float pl[HEADS], pr[HEADS];
#pragma unroll
        for (int h = 0; h < HEADS; ++h) {
            pl[h] = acc[i][h * 4 + 0] * alr[h * 4 + 0] + acc[i][h * 4 + 1] * alr[h * 4 + 1] +
                    acc[i][h * 4 + 2] * alr[h * 4 + 2] + acc[i][h * 4 + 3] * alr[h * 4 + 3];
            pr[h] = acc[i][h * 4 + 0] * arr[h * 4 + 0] + acc[i][h * 4 + 1] * arr[h * 4 + 1] +
                    acc[i][h * 4 + 2] * arr[h * 4 + 2] + acc[i][h * 4 + 3] * arr[h * 4 + 3];
        }
#pragma unroll
        for (int m = 1; m < 16; m <<= 1) {
#pragma unroll
            for (int h = 0; h < HEADS; ++h) {
                pl[h] += __shfl_xor(pl[h], m, 64);
                pr[h] += __shfl_xor(pr[h], m, 64);
            }
        }
        if ((tid & 15) == 0 && live) {
#pragma unroll
            for (int h = 0; h < HEADS; ++h) {
                elr[(size_t)row * 8 + h] = pl[h];
                elr[(size_t)row * 8 + 4 + h] = pr[h];
            }
        }
    }
}

// ---------------- layer-0 softmax+aggregate; epilogue emits h1(bf16) + el1/er1 --

__global__ __launch_bounds__(256) void k_agg0(const unsigned short* __restrict__ z16,
                                              const float* __restrict__ elr0,
                                              const int* __restrict__ rowstart,
                                              const int* __restrict__ csr_src,
                                              const float* __restrict__ bias,
                                              const float* __restrict__ wlr1,
                                              unsigned short* __restrict__ h1b,
                                              float* __restrict__ elr1, int N) {
    int node = blockIdx.x * 4 + (threadIdx.x >> 6);
    int lane = threadIdx.x & 63;
    if (node >= N) return;
    float4 wl4 = *(const float4*)(wlr1 + lane * 8);
    float4 wr4 = *(const float4*)(wlr1 + lane * 8 + 4);
    int s = rowstart[node], e = rowstart[node + 1];
    float4 erv = *(const float4*)(elr0 + (size_t)node * 8 + 4);
    float s0 = 0.f, s1 = 0.f, s2 = 0.f;
    float a0 = 0.f, a1 = 0.f, a2 = 0.f;
    int i = s;
    for (; i + 4 <= e; i += 4) {
        int sr0 = csr_src[i];
        int sr1 = csr_src[i + 1];
        int sr2 = csr_src[i + 2];
        int sr3 = csr_src[i + 3];
        float4 el0 = *(const float4*)(elr0 + (size_t)sr0 * 8);
        float4 el1 = *(const float4*)(elr0 + (size_t)sr1 * 8);
        float4 el2 = *(const float4*)(elr0 + (size_t)sr2 * 8);
        float4 el3 = *(const float4*)(elr0 + (size_t)sr3 * 8);
        const unsigned short* zr0 = z16 + (size_t)sr0 * OUTW;
        const unsigned short* zr1 = z16 + (size_t)sr1 * OUTW;
        const unsigned short* zr2 = z16 + (size_t)sr2 * OUTW;
        const unsigned short* zr3 = z16 + (size_t)sr3 * OUTW;
        unsigned short p00 = zr0[lane], p01 = zr0[HID + lane], p02 = zr0[2 * HID + lane];
        unsigned short p10 = zr1[lane], p11 = zr1[HID + lane], p12 = zr1[2 * HID + lane];
        unsigned short p20 = zr2[lane], p21 = zr2[HID + lane], p22 = zr2[2 * HID + lane];
        unsigned short p30 = zr3[lane], p31 = zr3[HID + lane], p32 = zr3[2 * HID + lane];
        float w00 = __expf(lrelu(el0.x + erv.x));
        float w01 = __expf(lrelu(el0.y + erv.y));
        float w02 = __expf(lrelu(el0.z + erv.z));
        float w10 = __expf(lrelu(el1.x + erv.x));
        float w11 = __expf(lrelu(el1.y + erv.y));
        float w12 = __expf(lrelu(el1.z + erv.z));
        float w20 = __expf(lrelu(el2.x + erv.x));
        float w21 = __expf(lrelu(el2.y + erv.y));
        float w22 = __expf(lrelu(el2.z + erv.z));
        float w30 = __expf(lrelu(el3.x + erv.x));
        float w31 = __expf(lrelu(el3.y + erv.y));
        float w32 = __expf(lrelu(el3.z + erv.z));
        s0 += (w00 + w10) + (w20 + w30);
        s1 += (w01 + w11) + (w21 + w31);
        s2 += (w02 + w12) + (w22 + w32);
        a0 = fmaf(w00, bf2f(p00), a0);
        a1 = fmaf(w01, bf2f(p01), a1);
        a2 = fmaf(w02, bf2f(p02), a2);
        a0 = fmaf(w10, bf2f(p10), a0);
        a1 = fmaf(w11, bf2f(p11), a1);
        a2 = fmaf(w12, bf2f(p12), a2);
        a0 = fmaf(w20, bf2f(p20), a0);
        a1 = fmaf(w21, bf2f(p21), a1);
        a2 = fmaf(w22, bf2f(p22), a2);
        a0 = fmaf(w30, bf2f(p30), a0);
        a1 = fmaf(w31, bf2f(p31), a1);
        a2 = fmaf(w32, bf2f(p32), a2);
    }
    for (; i < e; ++i) {
        int sr = csr_src[i];
        float4 elv = *(const float4*)(elr0 + (size_t)sr * 8);
        const unsigned short* zr = z16 + (size_t)sr * OUTW;
        float w0 = __expf(lrelu(elv.x + erv.x));
        float w1 = __expf(lrelu(elv.y + erv.y));
        float w2 = __expf(lrelu(elv.z + erv.z));
        s0 += w0; s1 += w1; s2 += w2;
        a0 = fmaf(w0, bf2f(zr[lane]), a0);
        a1 = fmaf(w1, bf2f(zr[HID + lane]), a1);
        a2 = fmaf(w2, bf2f(zr[2 * HID + lane]), a2);
    }
    float r = bias[lane] + bias[HID + lane] + bias[2 * HID + lane];
    if (s0 > 0.f) r += a0 / s0;
    if (s1 > 0.f) r += a1 / s1;
    if (s2 > 0.f) r += a2 / s2;
    r *= (1.f / 3.f);

    h1b[(size_t)node * HID + lane] = f2bf(r);
    float pl0 = r * wl4.x, pl1 = r * wl4.y, pl2 = r * wl4.z;
    float pr0 = r * wr4.x, pr1 = r * wr4.y, pr2 = r * wr4.z;
#pragma unroll
    for (int m = 1; m < 64; m <<= 1) {
        pl0 += __shfl_xor(pl0, m, 64);
        pl1 += __shfl_xor(pl1, m, 64);
        pl2 += __shfl_xor(pl2, m, 64);
        pr0 += __shfl_xor(pr0, m, 64);
        pr1 += __shfl_xor(pr1, m, 64);
        pr2 += __shfl_xor(pr2, m, 64);
    }
    if (lane == 0) {
        elr1[(size_t)node * 8 + 0] = pl0;
        elr1[(size_t)node * 8 + 1] = pl1;
        elr1[(size_t)node * 8 + 2] = pl2;
        elr1[(size_t)node * 8 + 4] = pr0;
        elr1[(size_t)node * 8 + 5] = pr1;
        elr1[(size_t)node * 8 + 6] = pr2;
    }
}

// ---------------- layer-1: ONE dst-grouped pass over the CSR -------------------
// Global 192-vector: macc[h][:] = sum_dst (1/s_dst,h) * sum_{e@dst} w_e * h1[src_e].
// Wave per dst node (4/block); per edge: 16B elr1 gather + 128B h1b row gather.
// Denominator computed in the same pass with the same exp. No CSC, no scattered
// atomics: per-wave registers -> LDS block reduce -> 192 atomics per block.

__global__ __launch_bounds__(256) void k_lsum(const unsigned short* __restrict__ h1b,
                                              const float* __restrict__ elr1,
                                              const int* __restrict__ rowstart,
                                              const int* __restrict__ csr_src,
                                              float* __restrict__ macc, int N) {
    int lane = threadIdx.x & 63;
    int w = threadIdx.x >> 6;
    int node = blockIdx.x * 4 + w;
    float g0 = 0.f, g1 = 0.f, g2 = 0.f;
    if (node < N) {
        int s = rowstart[node], e = rowstart[node + 1];
        if (s < e) {
            float4 erv = *(const float4*)(elr1 + (size_t)node * 8 + 4);
            float s0 = 0.f, s1 = 0.f, s2 = 0.f;
            float a0 = 0.f, a1 = 0.f, a2 = 0.f;
            int i = s;
            for (; i + 4 <= e; i += 4) {
                int sr0 = csr_src[i];
                int sr1 = csr_src[i + 1];
                int sr2 = csr_src[i + 2];
                int sr3 = csr_src[i + 3];
                float4 el0 = *(const float4*)(elr1 + (size_t)sr0 * 8);
                float4 el1 = *(const float4*)(elr1 + (size_t)sr1 * 8);
                float4 el2 = *(const float4*)(elr1 + (size_t)sr2 * 8);
                float4 el3 = *(const float4*)(elr1 + (size_t)sr3 * 8);
                float v0 = bf2f(h1b[(size_t)sr0 * HID + lane]);
                float v1 = bf2f(h1b[(size_t)sr1 * HID + lane]);
                float v2 = bf2f(h1b[(size_t)sr2 * HID + lane]);
                float v3 = bf2f(h1b[(size_t)sr3 * HID + lane]);
                float w00 = __expf(lrelu(el0.x + erv.x));
                float w01 = __expf(lrelu(el0.y + erv.y));
                float w02 = __expf(lrelu(el0.z + erv.z));
                float w10 = __expf(lrelu(el1.x + erv.x));
                float w11 = __expf(lrelu(el1.y + erv.y));
                float w12 = __expf(lrelu(el1.z + erv.z));
                float w20 = __expf(lrelu(el2.x + erv.x));
                float w21 = __expf(lrelu(el2.y + erv.y));
                float w22 = __expf(lrelu(el2.z + erv.z));
                float w30 = __expf(lrelu(el3.x + erv.x));
                float w31 = __expf(lrelu(el3.y + erv.y));
                float w32 = __expf(lrelu(el3.z + erv.z));
                s0 += (w00 + w10) + (w20 + w30);
                s1 += (w01 + w11) + (w21 + w31);
                s2 += (w02 + w12) + (w22 + w32);
                a0 = fmaf(w00, v0, a0);
                a1 = fmaf(w01, v0, a1);
                a2 = fmaf(w02, v0, a2);
                a0 = fmaf(w10, v1, a0);
                a1 = fmaf(w11, v1, a1);
                a2 = fmaf(w12, v1, a2);
                a0 = fmaf(w20, v2, a0);
                a1 = fmaf(w21, v2, a1);
                a2 = fmaf(w22, v2, a2);
                a0 = fmaf(w30, v3, a0);
                a1 = fmaf(w31, v3, a1);
                a2 = fmaf(w32, v3, a2);
            }
            for (; i < e; ++i) {
                int sr = csr_src[i];
                float4 elv = *(const float4*)(elr1 + (size_t)sr * 8);
                float v = bf2f(h1b[(size_t)sr * HID + lane]);
                float w0 = __expf(lrelu(elv.x + erv.x));
                float w1 = __expf(lrelu(elv.y + erv.y));
                float w2 = __expf(lrelu(elv.z + erv.z));
                s0 += w0; s1 += w1; s2 += w2;
                a0 = fmaf(w0, v, a0);
                a1 = fmaf(w1, v, a1);
                a2 = fmaf(w2, v, a2);
            }
            g0 = s0 > 0.f ? a0 / s0 : 0.f;
            g1 = s1 > 0.f ? a1 / s1 : 0.f;
            g2 = s2 > 0.f ? a2 / s2 : 0.f;
        }
    }
    __shared__ float sh[4][3][64];
    sh[w][0][lane] = g0;
    sh[w][1][lane] = g1;
    sh[w][2][lane] = g2;
    __syncthreads();
    if (w == 0) {
        float t0 = sh[0][0][lane] + sh[1][0][lane] + sh[2][0][lane] + sh[3][0][lane];
        float t1 = sh[0][1][lane] + sh[1][1][lane] + sh[2][1][lane] + sh[3][1][lane];
        float t2 = sh[0][2][lane] + sh[1][2][lane] + sh[2][2][lane] + sh[3][2][lane];
        atomicAdd(&macc[0 * HID + lane], t0);
        atomicAdd(&macc[1 * HID + lane], t1);
        atomicAdd(&macc[2 * HID + lane], t2);
    }
}

// ---------------- final: out[f] = macc @ W1_stacked /(3N) + mean bias ----------

__global__ void k_final(const float* __restrict__ macc, const float* __restrict__ W1,
                        const float* __restrict__ b1, float* __restrict__ out, int N) {
    int f = threadIdx.x;
    if (f >= HID) return;
    float s = 0.f;
#pragma unroll
    for (int hh = 0; hh < HEADS; ++hh)
        for (int k = 0; k < HID; ++k)
            s = fmaf(macc[hh * HID + k], W1[k * OUTW + hh * HID + f], s);
    float bb = b1[f] + b1[HID + f] + b1[2 * HID + f];
    out[f] = s / (3.0f * (float)N) + bb * (1.f / 3.f);
}

// ---------------- launch ----------------

extern "C" void kernel_launch(void* const* d_in, const int* in_sizes, int n_in,
                              void* d_out, int out_size, void* d_ws, size_t ws_size,
                              hipStream_t stream) {
    const float* h   = (const float*)d_in[0];
    const int* src   = (const int*)d_in[1];
    const int* dst   = (const int*)d_in[2];
    const float* W0  = (const float*)d_in[3];
    const float* al0 = (const float*)d_in[4];
    const float* ar0 = (const float*)d_in[5];
    const float* b0  = (const float*)d_in[6];
    const float* W1  = (const float*)d_in[7];
    const float* al1 = (const float*)d_in[8];
    const float* ar1 = (const float*)d_in[9];
    const float* b1  = (const float*)d_in[10];
    float* out = (float*)d_out;

    const int N = in_sizes[0] / NS;
    const int E = in_sizes[1];

    char* ws = (char*)d_ws;
    size_t off = 0;
    auto alloc = [&](size_t bytes) {
        size_t r = off;
        off = (off + bytes + 255) & ~(size_t)255;
        return r;
    };
    unsigned short* z16 = (unsigned short*)(ws + alloc((size_t)N * OUTW * 2));
    unsigned short* h1b = (unsigned short*)(ws + alloc((size_t)N * HID * 2));
    float* elr0     = (float*)(ws + alloc((size_t)N * 8 * 4));
    float* elr1     = (float*)(ws + alloc((size_t)N * 8 * 4));
    float* macc     = (float*)(ws + alloc(OUTW * 4));
    int* cnt        = (int*)(ws + alloc((size_t)N * 4));
    int* rowstart   = (int*)(ws + alloc((size_t)(N + 1) * 4));
    int* cursor     = (int*)(ws + alloc((size_t)N * 4));
    int* csr_src    = (int*)(ws + alloc((size_t)E * 4));
    int* blocksums  = (int*)(ws + alloc(4096));
    float* wlr1     = (float*)(ws + alloc(64 * 8 * 4));

    const int nbScan = (N + 1023) / 1024;

    // CSR build (by dst) + zero macc
    k_zero_int<<<256, 256, 0, stream>>>(cnt, N);
    k_zero_int<<<1, 256, 0, stream>>>((int*)macc, OUTW);
    k_hist<<<512, 256, 0, stream>>>(dst, cnt, E);
    k_scan1<<<nbScan, 256, 0, stream>>>(cnt, rowstart, blocksums, N);
    k_scan2<<<1, 64, 0, stream>>>(blocksums, nbScan);
    k_scan3<<<(N + 255) / 256, 256, 0, stream>>>(rowstart, blocksums, cursor, N, E);
    k_scatter<<<512, 256, 0, stream>>>(src, dst, cursor, csr_src, E);
    k_prep<<<1, 192, 0, stream>>>(W1, al1, ar1, wlr1);

    // layer 0
    k_gemm4<NS><<<(N + 127) / 128, 256, 0, stream>>>(h, W0, al0, ar0, z16, elr0, N);
    k_agg0<<<(N + 3) / 4, 256, 0, stream>>>(z16, elr0, rowstart, csr_src, b0, wlr1,
                                            h1b, elr1, N);

    // layer 1 (collapsed): single dst-grouped pass -> global vector -> matvec
    k_lsum<<<(N + 3) / 4, 256, 0, stream>>>(h1b, elr1, rowstart, csr_src, macc, N);
    k_final<<<1, 64, 0, stream>>>(macc, W1, b1, out, N);
}

// Round 10
// 460.267 us; speedup vs baseline: 2.0028x; 2.0028x over previous
//
#include <hip/hip_runtime.h>
#include <hip/hip_bf16.h>

#define HEADS 3
#define HID 64
#define OUTW (HEADS * HID)   // 192
#define NS 128               // node feature size

__device__ __forceinline__ float lrelu(float x) {
    return x > 0.f ? x : 0.2f * x;
}

__device__ __forceinline__ unsigned short f2bf(float f) {
    unsigned u = __float_as_uint(f);
    u += 0x7fff + ((u >> 16) & 1);   // RNE
    return (unsigned short)(u >> 16);
}

__device__ __forceinline__ float bf2f(unsigned short u) {
    return __uint_as_float((unsigned)u << 16);
}

// ---------------- CSR build (by dst) ----------------

__global__ void k_zero_int(int* p, int n) {
    int i = blockIdx.x * blockDim.x + threadIdx.x;
    for (; i < n; i += gridDim.x * blockDim.x) p[i] = 0;
}

__global__ void k_hist(const int* __restrict__ key, int* __restrict__ cnt, int E) {
    int i = blockIdx.x * blockDim.x + threadIdx.x;
    for (; i < E; i += gridDim.x * blockDim.x) atomicAdd(&cnt[key[i]], 1);
}

__global__ void k_scan1(const int* __restrict__ cnt, int* __restrict__ rowstart,
                        int* __restrict__ blocksums, int N) {
    int t = threadIdx.x;
    int base = blockIdx.x * 1024 + t * 4;
    int v[4];
    int ts = 0;
#pragma unroll
    for (int j = 0; j < 4; ++j) {
        v[j] = (base + j < N) ? cnt[base + j] : 0;
        ts += v[j];
    }
    __shared__ int sh[256];
    sh[t] = ts;
    __syncthreads();
    for (int off = 1; off < 256; off <<= 1) {
        int x = 0;
        if (t >= off) x = sh[t - off];
        __syncthreads();
        if (t >= off) sh[t] += x;
        __syncthreads();
    }
    int excl = sh[t] - ts;
    if (t == 255) blocksums[blockIdx.x] = sh[255];
    int run = excl;
#pragma unroll
    for (int j = 0; j < 4; ++j) {
        if (base + j < N) rowstart[base + j] = run;
        run += v[j];
    }
}

__global__ void k_scan2(int* blocksums, int nb) {
    if (blockIdx.x == 0 && threadIdx.x == 0) {
        int s = 0;
        for (int i = 0; i < nb; ++i) {
            int v = blocksums[i];
            blocksums[i] = s;
            s += v;
        }
    }
}

__global__ void k_scan3(int* __restrict__ rowstart, const int* __restrict__ blocksums,
                        int* __restrict__ cursor, int N, int E) {
    int i = blockIdx.x * blockDim.x + threadIdx.x;
    if (i < N) {
        int v = rowstart[i] + blocksums[i >> 10];
        rowstart[i] = v;
        cursor[i] = v;
    }
    if (i == 0) rowstart[N] = E;
}

__global__ void k_scatter(const int* __restrict__ val, const int* __restrict__ key,
                          int* __restrict__ cursor, int* __restrict__ outidx, int E) {
    int i = blockIdx.x * blockDim.x + threadIdx.x;
    for (; i < E; i += gridDim.x * blockDim.x) {
        int d = key[i];
        int p = atomicAdd(&cursor[d], 1);
        outidx[p] = val[i];
    }
}

// ---------------- prep: wl1/wr1[k,h] = sum_f W1[k, h*64+f] * al1/ar1[h,f] ------

__global__ void k_prep(const float* __restrict__ W1, const float* __restrict__ al1,
                       const float* __restrict__ ar1, float* __restrict__ wlr1) {
    int t = threadIdx.x;
    if (t >= 192) return;
    int k = t & 63, hh = t >> 6;
    float sl = 0.f, sr = 0.f;
#pragma unroll 8
    for (int f = 0; f < 64; ++f) {
        float w = W1[k * OUTW + hh * 64 + f];
        sl = fmaf(w, al1[hh * 64 + f], sl);
        sr = fmaf(w, ar1[hh * 64 + f], sr);
    }
    wlr1[k * 8 + hh] = sl;
    wlr1[k * 8 + 4 + hh] = sr;
}

// ---------------- GEMM0: Z16[M,192](bf16) = X[M,128] @ W0, fused el0/er0 --------

template <int K>
__global__ __launch_bounds__(256, 2) void k_gemm4(const float* __restrict__ X,
                                                  const float* __restrict__ W,
                                                  const float* __restrict__ al,
                                                  const float* __restrict__ ar,
                                                  unsigned short* __restrict__ Z16,
                                                  float* __restrict__ elr,
                                                  int M) {
    constexpr int NT = K / 16;
    __shared__ __align__(16) float At[2][16 * 132];
    __shared__ __align__(16) float Bs[2][16 * 192];
    const int tid = threadIdx.x;
    const int tx = tid & 15;
    const int ty = tid >> 4;
    const int r0 = blockIdx.x * 128;

    float acc[8][12];
#pragma unroll
    for (int i = 0; i < 8; ++i)
#pragma unroll
        for (int j = 0; j < 12; ++j) acc[i][j] = 0.f;

    const int arow = tid >> 2;
    const int akb = (tid & 3) * 4;

    float4 aR[2], bR[3];

    auto loadA = [&](int k0) {
#pragma unroll
        for (int i = 0; i < 2; ++i) {
            int gr = r0 + arow + i * 64;
            if (gr >= M) gr = M - 1;
            aR[i] = *(const float4*)(X + (size_t)gr * K + k0 + akb);
        }
    };
    auto loadB = [&](int k0) {
#pragma unroll
        for (int i = 0; i < 3; ++i)
            bR[i] = *(const float4*)(W + (size_t)k0 * OUTW + (tid + i * 256) * 4);
    };
    auto writeA = [&](int buf) {
#pragma unroll
        for (int i = 0; i < 2; ++i) {
            int row = arow + i * 64;
            At[buf][(akb + 0) * 132 + row] = aR[i].x;
            At[buf][(akb + 1) * 132 + row] = aR[i].y;
            At[buf][(akb + 2) * 132 + row] = aR[i].z;
            At[buf][(akb + 3) * 132 + row] = aR[i].w;
        }
    };
    auto writeB = [&](int buf) {
#pragma unroll
        for (int i = 0; i < 3; ++i)
            *(float4*)(&Bs[buf][(tid + i * 256) * 4]) = bR[i];
    };

    loadA(0);
    loadB(0);
    writeA(0);
    writeB(0);
    __syncthreads();

    int cur = 0;
    for (int t = 0; t < NT; ++t) {
        if (t + 1 < NT) {
            loadA((t + 1) * 16);
            loadB((t + 1) * 16);
        }
#pragma unroll 8
        for (int k = 0; k < 16; ++k) {
            float a[8], b[12];
            *(float4*)&a[0] = *(const float4*)&At[cur][k * 132 + ty * 8];
            *(float4*)&a[4] = *(const float4*)&At[cur][k * 132 + ty * 8 + 4];
            *(float4*)&b[0] = *(const float4*)&Bs[cur][k * OUTW + tx * 4];
            *(float4*)&b[4] = *(const float4*)&Bs[cur][k * OUTW + 64 + tx * 4];
            *(float4*)&b[8] = *(const float4*)&Bs[cur][k * OUTW + 128 + tx * 4];
#pragma unroll
            for (int i = 0; i < 8; ++i)
#pragma unroll
                for (int j = 0; j < 12; ++j) acc[i][j] = fmaf(a[i], b[j], acc[i][j]);
        }
        if (t + 1 < NT) {
            writeA(cur ^ 1);
            writeB(cur ^ 1);
        }
        __syncthreads();
        cur ^= 1;
    }

    float alr[12], arr[12];
#pragma unroll
    for (int h = 0; h < HEADS; ++h)
#pragma unroll
        for (int c = 0; c < 4; ++c) {
            alr[h * 4 + c] = al[h * 64 + tx * 4 + c];
            arr[h * 4 + c] = ar[h * 64 + tx * 4 + c];
        }

#pragma unroll
    for (int i = 0; i < 8; ++i) {
        int row = r0 + ty * 8 + i;
        bool live = row < M;
        if (live) {
#pragma unroll
            for (int h = 0; h < HEADS; ++h) {
                ushort4 v;
                v.x = f2bf(acc[i][h * 4 + 0]);
                v.y = f2bf(acc[i][h * 4 + 1]);
                v.z = f2bf(acc[i][h * 4 + 2]);
                v.w = f2bf(acc[i][h * 4 + 3]);
                *(ushort4*)(Z16 + (size_t)row * OUTW + h * 64 + tx * 4) = v;
            }
        }
        float pl[HEADS], pr[HEADS];
#pragma unroll
        for (int h = 0; h < HEADS; ++h) {
            pl[h] = acc[i][h * 4 + 0] * alr[h * 4 + 0] + acc[i][h * 4 + 1] * alr[h * 4 + 1] +
                    acc[i][h * 4 + 2] * alr[h * 4 + 2] + acc[i][h * 4 + 3] * alr[h * 4 + 3];
            pr[h] = acc[i][h * 4 + 0] * arr[h * 4 + 0] + acc[i][h * 4 + 1] * arr[h * 4 + 1] +
                    acc[i][h * 4 + 2] * arr[h * 4 + 2] + acc[i][h * 4 + 3] * arr[h * 4 + 3];
        }
#pragma unroll
        for (int m = 1; m < 16; m <<= 1) {
#pragma unroll
            for (int h = 0; h < HEADS; ++h) {
                pl[h] += __shfl_xor(pl[h], m, 64);
                pr[h] += __shfl_xor(pr[h], m, 64);
            }
        }
        if ((tid & 15) == 0 && live) {
#pragma unroll
            for (int h = 0; h < HEADS; ++h) {
                elr[(size_t)row * 8 + h] = pl[h];
                elr[(size_t)row * 8 + 4 + h] = pr[h];
            }
        }
    }
}

// ---------------- layer-0 softmax+aggregate; epilogue emits h1(bf16) + el1/er1 --

__global__ __launch_bounds__(256) void k_agg0(const unsigned short* __restrict__ z16,
                                              const float* __restrict__ elr0,
                                              const int* __restrict__ rowstart,
                                              const int* __restrict__ csr_src,
                                              const float* __restrict__ bias,
                                              const float* __restrict__ wlr1,
                                              unsigned short* __restrict__ h1b,
                                              float* __restrict__ elr1, int N) {
    int node = blockIdx.x * 4 + (threadIdx.x >> 6);
    int lane = threadIdx.x & 63;
    if (node >= N) return;
    float4 wl4 = *(const float4*)(wlr1 + lane * 8);
    float4 wr4 = *(const float4*)(wlr1 + lane * 8 + 4);
    int s = rowstart[node], e = rowstart[node + 1];
    float4 erv = *(const float4*)(elr0 + (size_t)node * 8 + 4);
    float s0 = 0.f, s1 = 0.f, s2 = 0.f;
    float a0 = 0.f, a1 = 0.f, a2 = 0.f;
    int i = s;
    for (; i + 4 <= e; i += 4) {
        int sr0 = csr_src[i];
        int sr1 = csr_src[i + 1];
        int sr2 = csr_src[i + 2];
        int sr3 = csr_src[i + 3];
        float4 el0 = *(const float4*)(elr0 + (size_t)sr0 * 8);
        float4 el1 = *(const float4*)(elr0 + (size_t)sr1 * 8);
        float4 el2 = *(const float4*)(elr0 + (size_t)sr2 * 8);
        float4 el3 = *(const float4*)(elr0 + (size_t)sr3 * 8);
        const unsigned short* zr0 = z16 + (size_t)sr0 * OUTW;
        const unsigned short* zr1 = z16 + (size_t)sr1 * OUTW;
        const unsigned short* zr2 = z16 + (size_t)sr2 * OUTW;
        const unsigned short* zr3 = z16 + (size_t)sr3 * OUTW;
        unsigned short p00 = zr0[lane], p01 = zr0[HID + lane], p02 = zr0[2 * HID + lane];
        unsigned short p10 = zr1[lane], p11 = zr1[HID + lane], p12 = zr1[2 * HID + lane];
        unsigned short p20 = zr2[lane], p21 = zr2[HID + lane], p22 = zr2[2 * HID + lane];
        unsigned short p30 = zr3[lane], p31 = zr3[HID + lane], p32 = zr3[2 * HID + lane];
        float w00 = __expf(lrelu(el0.x + erv.x));
        float w01 = __expf(lrelu(el0.y + erv.y));
        float w02 = __expf(lrelu(el0.z + erv.z));
        float w10 = __expf(lrelu(el1.x + erv.x));
        float w11 = __expf(lrelu(el1.y + erv.y));
        float w12 = __expf(lrelu(el1.z + erv.z));
        float w20 = __expf(lrelu(el2.x + erv.x));
        float w21 = __expf(lrelu(el2.y + erv.y));
        float w22 = __expf(lrelu(el2.z + erv.z));
        float w30 = __expf(lrelu(el3.x + erv.x));
        float w31 = __expf(lrelu(el3.y + erv.y));
        float w32 = __expf(lrelu(el3.z + erv.z));
        s0 += (w00 + w10) + (w20 + w30);
        s1 += (w01 + w11) + (w21 + w31);
        s2 += (w02 + w12) + (w22 + w32);
        a0 = fmaf(w00, bf2f(p00), a0);
        a1 = fmaf(w01, bf2f(p01), a1);
        a2 = fmaf(w02, bf2f(p02), a2);
        a0 = fmaf(w10, bf2f(p10), a0);
        a1 = fmaf(w11, bf2f(p11), a1);
        a2 = fmaf(w12, bf2f(p12), a2);
        a0 = fmaf(w20, bf2f(p20), a0);
        a1 = fmaf(w21, bf2f(p21), a1);
        a2 = fmaf(w22, bf2f(p22), a2);
        a0 = fmaf(w30, bf2f(p30), a0);
        a1 = fmaf(w31, bf2f(p31), a1);
        a2 = fmaf(w32, bf2f(p32), a2);
    }
    for (; i < e; ++i) {
        int sr = csr_src[i];
        float4 elv = *(const float4*)(elr0 + (size_t)sr * 8);
        const unsigned short* zr = z16 + (size_t)sr * OUTW;
        float w0 = __expf(lrelu(elv.x + erv.x));
        float w1 = __expf(lrelu(elv.y + erv.y));
        float w2 = __expf(lrelu(elv.z + erv.z));
        s0 += w0; s1 += w1; s2 += w2;
        a0 = fmaf(w0, bf2f(zr[lane]), a0);
        a1 = fmaf(w1, bf2f(zr[HID + lane]), a1);
        a2 = fmaf(w2, bf2f(zr[2 * HID + lane]), a2);
    }
    float r = bias[lane] + bias[HID + lane] + bias[2 * HID + lane];
    if (s0 > 0.f) r += a0 / s0;
    if (s1 > 0.f) r += a1 / s1;
    if (s2 > 0.f) r += a2 / s2;
    r *= (1.f / 3.f);

    h1b[(size_t)node * HID + lane] = f2bf(r);
    float pl0 = r * wl4.x, pl1 = r * wl4.y, pl2 = r * wl4.z;
    float pr0 = r * wr4.x, pr1 = r * wr4.y, pr2 = r * wr4.z;
#pragma unroll
    for (int m = 1; m < 64; m <<= 1) {
        pl0 += __shfl_xor(pl0, m, 64);
        pl1 += __shfl_xor(pl1, m, 64);
        pl2 += __shfl_xor(pl2, m, 64);
        pr0 += __shfl_xor(pr0, m, 64);
        pr1 += __shfl_xor(pr1, m, 64);
        pr2 += __shfl_xor(pr2, m, 64);
    }
    if (lane == 0) {
        elr1[(size_t)node * 8 + 0] = pl0;
        elr1[(size_t)node * 8 + 1] = pl1;
        elr1[(size_t)node * 8 + 2] = pl2;
        elr1[(size_t)node * 8 + 4] = pr0;
        elr1[(size_t)node * 8 + 5] = pr1;
        elr1[(size_t)node * 8 + 6] = pr2;
    }
}

// ---------------- layer-1: ONE dst-grouped pass, GRID-STRIDE -------------------
// macc[h][:] = sum_dst (1/s_dst,h) * sum_{e@dst} w_e * h1[src_e].
// Wave per dst node, but a FIXED 512-block grid; each wave accumulates its
// per-node results in registers across ~N/2048 nodes, then ONE block-reduce +
// 192 atomics per block (98k total -- round-9's 4.8M same-address atomics at
// ~126ns each were the 606us disaster).

__global__ __launch_bounds__(256) void k_lsum(const unsigned short* __restrict__ h1b,
                                              const float* __restrict__ elr1,
                                              const int* __restrict__ rowstart,
                                              const int* __restrict__ csr_src,
                                              float* __restrict__ macc, int N) {
    int lane = threadIdx.x & 63;
    int w = threadIdx.x >> 6;
    int wid = (blockIdx.x * blockDim.x + threadIdx.x) >> 6;
    int nw = (gridDim.x * blockDim.x) >> 6;
    float g0 = 0.f, g1 = 0.f, g2 = 0.f;
    for (int node = wid; node < N; node += nw) {
        int s = rowstart[node], e = rowstart[node + 1];
        if (s == e) continue;
        float4 erv = *(const float4*)(elr1 + (size_t)node * 8 + 4);
        float s0 = 0.f, s1 = 0.f, s2 = 0.f;
        float a0 = 0.f, a1 = 0.f, a2 = 0.f;
        int i = s;
        for (; i + 4 <= e; i += 4) {
            int sr0 = csr_src[i];
            int sr1 = csr_src[i + 1];
            int sr2 = csr_src[i + 2];
            int sr3 = csr_src[i + 3];
            float4 el0 = *(const float4*)(elr1 + (size_t)sr0 * 8);
            float4 el1 = *(const float4*)(elr1 + (size_t)sr1 * 8);
            float4 el2 = *(const float4*)(elr1 + (size_t)sr2 * 8);
            float4 el3 = *(const float4*)(elr1 + (size_t)sr3 * 8);
            float v0 = bf2f(h1b[(size_t)sr0 * HID + lane]);
            float v1 = bf2f(h1b[(size_t)sr1 * HID + lane]);
            float v2 = bf2f(h1b[(size_t)sr2 * HID + lane]);
            float v3 = bf2f(h1b[(size_t)sr3 * HID + lane]);
            float w00 = __expf(lrelu(el0.x + erv.x));
            float w01 = __expf(lrelu(el0.y + erv.y));
            float w02 = __expf(lrelu(el0.z + erv.z));
            float w10 = __expf(lrelu(el1.x + erv.x));
            float w11 = __expf(lrelu(el1.y + erv.y));
            float w12 = __expf(lrelu(el1.z + erv.z));
            float w20 = __expf(lrelu(el2.x + erv.x));
            float w21 = __expf(lrelu(el2.y + erv.y));
            float w22 = __expf(lrelu(el2.z + erv.z));
            float w30 = __expf(lrelu(el3.x + erv.x));
            float w31 = __expf(lrelu(el3.y + erv.y));
            float w32 = __expf(lrelu(el3.z + erv.z));
            s0 += (w00 + w10) + (w20 + w30);
            s1 += (w01 + w11) + (w21 + w31);
            s2 += (w02 + w12) + (w22 + w32);
            a0 = fmaf(w00, v0, a0);
            a1 = fmaf(w01, v0, a1);
            a2 = fmaf(w02, v0, a2);
            a0 = fmaf(w10, v1, a0);
            a1 = fmaf(w11, v1, a1);
            a2 = fmaf(w12, v1, a2);
            a0 = fmaf(w20, v2, a0);
            a1 = fmaf(w21, v2, a1);
            a2 = fmaf(w22, v2, a2);
            a0 = fmaf(w30, v3, a0);
            a1 = fmaf(w31, v3, a1);
            a2 = fmaf(w32, v3, a2);
        }
        for (; i < e; ++i) {
            int sr = csr_src[i];
            float4 elv = *(const float4*)(elr1 + (size_t)sr * 8);
            float v = bf2f(h1b[(size_t)sr * HID + lane]);
            float w0 = __expf(lrelu(elv.x + erv.x));
            float w1 = __expf(lrelu(elv.y + erv.y));
            float w2 = __expf(lrelu(elv.z + erv.z));
            s0 += w0; s1 += w1; s2 += w2;
            a0 = fmaf(w0, v, a0);
            a1 = fmaf(w1, v, a1);
            a2 = fmaf(w2, v, a2);
        }
        if (s0 > 0.f) g0 += a0 / s0;
        if (s1 > 0.f) g1 += a1 / s1;
        if (s2 > 0.f) g2 += a2 / s2;
    }
    __shared__ float sh[4][3][64];
    sh[w][0][lane] = g0;
    sh[w][1][lane] = g1;
    sh[w][2][lane] = g2;
    __syncthreads();
    if (w == 0) {
        float t0 = sh[0][0][lane] + sh[1][0][lane] + sh[2][0][lane] + sh[3][0][lane];
        float t1 = sh[0][1][lane] + sh[1][1][lane] + sh[2][1][lane] + sh[3][1][lane];
        float t2 = sh[0][2][lane] + sh[1][2][lane] + sh[2][2][lane] + sh[3][2][lane];
        atomicAdd(&macc[0 * HID + lane], t0);
        atomicAdd(&macc[1 * HID + lane], t1);
        atomicAdd(&macc[2 * HID + lane], t2);
    }
}

// ---------------- final: out[f] = macc @ W1_stacked /(3N) + mean bias ----------

__global__ void k_final(const float* __restrict__ macc, const float* __restrict__ W1,
                        const float* __restrict__ b1, float* __restrict__ out, int N) {
    int f = threadIdx.x;
    if (f >= HID) return;
    float s = 0.f;
#pragma unroll
    for (int hh = 0; hh < HEADS; ++hh)
        for (int k = 0; k < HID; ++k)
            s = fmaf(macc[hh * HID + k], W1[k * OUTW + hh * HID + f], s);
    float bb = b1[f] + b1[HID + f] + b1[2 * HID + f];
    out[f] = s / (3.0f * (float)N) + bb * (1.f / 3.f);
}

// ---------------- launch ----------------

extern "C" void kernel_launch(void* const* d_in, const int* in_sizes, int n_in,
                              void* d_out, int out_size, void* d_ws, size_t ws_size,
                              hipStream_t stream) {
    const float* h   = (const float*)d_in[0];
    const int* src   = (const int*)d_in[1];
    const int* dst   = (const int*)d_in[2];
    const float* W0  = (const float*)d_in[3];
    const float* al0 = (const float*)d_in[4];
    const float* ar0 = (const float*)d_in[5];
    const float* b0  = (const float*)d_in[6];
    const float* W1  = (const float*)d_in[7];
    const float* al1 = (const float*)d_in[8];
    const float* ar1 = (const float*)d_in[9];
    const float* b1  = (const float*)d_in[10];
    float* out = (float*)d_out;

    const int N = in_sizes[0] / NS;
    const int E = in_sizes[1];

    char* ws = (char*)d_ws;
    size_t off = 0;
    auto alloc = [&](size_t bytes) {
        size_t r = off;
        off = (off + bytes + 255) & ~(size_t)255;
        return r;
    };
    unsigned short* z16 = (unsigned short*)(ws + alloc((size_t)N * OUTW * 2));
    unsigned short* h1b = (unsigned short*)(ws + alloc((size_t)N * HID * 2));
    float* elr0     = (float*)(ws + alloc((size_t)N * 8 * 4));
    float* elr1     = (float*)(ws + alloc((size_t)N * 8 * 4));
    float* macc     = (float*)(ws + alloc(OUTW * 4));
    int* cnt        = (int*)(ws + alloc((size_t)N * 4));
    int* rowstart   = (int*)(ws + alloc((size_t)(N + 1) * 4));
    int* cursor     = (int*)(ws + alloc((size_t)N * 4));
    int* csr_src    = (int*)(ws + alloc((size_t)E * 4));
    int* blocksums  = (int*)(ws + alloc(4096));
    float* wlr1     = (float*)(ws + alloc(64 * 8 * 4));

    const int nbScan = (N + 1023) / 1024;

    // CSR build (by dst) + zero macc
    k_zero_int<<<256, 256, 0, stream>>>(cnt, N);
    k_zero_int<<<1, 256, 0, stream>>>((int*)macc, OUTW);
    k_hist<<<512, 256, 0, stream>>>(dst, cnt, E);
    k_scan1<<<nbScan, 256, 0, stream>>>(cnt, rowstart, blocksums, N);
    k_scan2<<<1, 64, 0, stream>>>(blocksums, nbScan);
    k_scan3<<<(N + 255) / 256, 256, 0, stream>>>(rowstart, blocksums, cursor, N, E);
    k_scatter<<<512, 256, 0, stream>>>(src, dst, cursor, csr_src, E);
    k_prep<<<1, 192, 0, stream>>>(W1, al1, ar1, wlr1);

    // layer 0
    k_gemm4<NS><<<(N + 127) / 128, 256, 0, stream>>>(h, W0, al0, ar0, z16, elr0, N);
    k_agg0<<<(N + 3) / 4, 256, 0, stream>>>(z16, elr0, rowstart, csr_src, b0, wlr1,
                                            h1b, elr1, N);

    // layer 1 (collapsed): grid-stride dst-grouped pass -> global vector -> matvec
    k_lsum<<<512, 256, 0, stream>>>(h1b, elr1, rowstart, csr_src, macc, N);
    k_final<<<1, 64, 0, stream>>>(macc, W1, b1, out, N);
}